// Round 2
// baseline (533.337 us; speedup 1.0000x reference)
//
#include <hip/hip_runtime.h>
#include <hip/hip_bf16.h>

// Problem constants
#define S_LEN 2048
#define HDIM  256
#define NHq   8
#define NKV   4
// scale = 1/sqrt(256) = 1/16 ; softcap 50 -> s_sc = 50*tanh(s/(16*50))

typedef __attribute__((ext_vector_type(8))) __bf16 bf16x8;
typedef __attribute__((ext_vector_type(4))) float  f32x4;

#define MFMA16x16(a,b,c) __builtin_amdgcn_mfma_f32_16x16x32_bf16((a),(b),(c),0,0,0)

__device__ __forceinline__ unsigned short f2b(float f) {
  return __builtin_bit_cast(unsigned short, (__bf16)f);
}
__device__ __forceinline__ float b2f(unsigned short u) {
  return (float)__builtin_bit_cast(__bf16, u);
}
__device__ __forceinline__ void gl_lds16(const void* g, void* l) {
  __builtin_amdgcn_global_load_lds(
      (const __attribute__((address_space(1))) unsigned int*)g,
      (__attribute__((address_space(3))) unsigned int*)l, 16, 0, 0);
}

// ---------------------------------------------------------------- cast kernel
__global__ __launch_bounds__(256) void cast_f32_bf16(
    const float* __restrict__ in, unsigned short* __restrict__ out, int n4) {
  int idx = blockIdx.x * blockDim.x + threadIdx.x;
  int stride = gridDim.x * blockDim.x;
  for (int i = idx; i < n4; i += stride) {
    float4 v = ((const float4*)in)[i];
    ushort4 o;
    o.x = f2b(v.x); o.y = f2b(v.y); o.z = f2b(v.z); o.w = f2b(v.w);
    ((ushort4*)out)[i] = o;
  }
}

// ---------------------------------------------------------------- GEMM (B^T)
// O[m,n] = sum_k A[m,k] * Bw[n,k].  A:[M][K] bf16, Bw:[N][K] bf16.
// 128x128 tile, BK=32, 4 waves each 64x64 (4x4 frags of 16x16x32).
// MODE 0: QKV fused output scatter (q:[b][h][s][d], k:[b][kv][s][d], vT:[b][kv][d][s])
// MODE 1: fp32 output [m][Nf]
template<int MODE>
__global__ __launch_bounds__(256) void gemm_bt(
    const unsigned short* __restrict__ A,
    const unsigned short* __restrict__ Bw,
    int K,
    unsigned short* __restrict__ q_out,
    unsigned short* __restrict__ k_out,
    unsigned short* __restrict__ vT_out,
    float* __restrict__ f_out, int Nf) {
  __shared__ unsigned short As[128 * 32];
  __shared__ unsigned short Bs[128 * 32];
  const int t = threadIdx.x;
  const int m0 = blockIdx.x * 128;
  const int n0 = blockIdx.y * 128;
  const int w = t >> 6, l = t & 63;
  const int wr = (w >> 1) * 64, wc = (w & 1) * 64;
  const int lr = l & 15, g = l >> 4;

  f32x4 acc[4][4] = {};

  // staging: linear LDS, 2-bit XOR swizzle (bits 4-5 ^= row&3) applied to SOURCE
  const int Lrow = t >> 2;                                  // tile row of this thread's 16B chunk
  const int Lkb  = ((t & 3) * 16) ^ ((Lrow & 3) << 4);      // swizzled k-byte within row
  const char* Ab  = (const char*)A  + ((size_t)(m0 + Lrow) * K) * 2 + Lkb;
  const char* Ab2 = Ab + (size_t)64 * K * 2;
  const char* Bb  = (const char*)Bw + ((size_t)(n0 + Lrow) * K) * 2 + Lkb;
  const char* Bb2 = Bb + (size_t)64 * K * 2;
  char* ldsA = (char*)As + t * 16;
  char* ldsB = (char*)Bs + t * 16;

  for (int k0 = 0; k0 < K; k0 += 32) {
    gl_lds16(Ab  + (size_t)k0 * 2, ldsA);
    gl_lds16(Ab2 + (size_t)k0 * 2, ldsA + 4096);
    gl_lds16(Bb  + (size_t)k0 * 2, ldsB);
    gl_lds16(Bb2 + (size_t)k0 * 2, ldsB + 4096);
    __syncthreads();
    bf16x8 af[4], bfr[4];
#pragma unroll
    for (int fm = 0; fm < 4; fm++) {
      int byteo = (wr + fm * 16 + lr) * 64 + g * 16;
      int sb = byteo ^ (((byteo >> 6) & 3) << 4);
      af[fm] = *(const bf16x8*)((const char*)As + sb);
    }
#pragma unroll
    for (int fn = 0; fn < 4; fn++) {
      int byteo = (wc + fn * 16 + lr) * 64 + g * 16;
      int sb = byteo ^ (((byteo >> 6) & 3) << 4);
      bfr[fn] = *(const bf16x8*)((const char*)Bs + sb);
    }
#pragma unroll
    for (int fm = 0; fm < 4; fm++)
#pragma unroll
      for (int fn = 0; fn < 4; fn++)
        acc[fm][fn] = MFMA16x16(af[fm], bfr[fn], acc[fm][fn]);
    __syncthreads();
  }

  // epilogue: C/D layout col=lane&15, row=(lane>>4)*4+reg
  const int mb = m0 + wr + g * 4;
  const int nb = n0 + wc + lr;
  if (MODE == 1) {
#pragma unroll
    for (int fm = 0; fm < 4; fm++)
#pragma unroll
      for (int fn = 0; fn < 4; fn++)
#pragma unroll
        for (int r = 0; r < 4; r++) {
          int m = mb + fm * 16 + r;
          int n = nb + fn * 16;
          f_out[(size_t)m * Nf + n] = acc[fm][fn][r];
        }
  } else {
#pragma unroll
    for (int fm = 0; fm < 4; fm++)
#pragma unroll
      for (int fn = 0; fn < 4; fn++)
#pragma unroll
        for (int r = 0; r < 4; r++) {
          int m = mb + fm * 16 + r;
          int n = nb + fn * 16;
          int b = m >> 11, s = m & 2047;
          unsigned short val = f2b(acc[fm][fn][r]);
          if (n0 < 2048) {           // Q region
            int h = n >> 8, d = n & 255;
            q_out[(((size_t)(b * 8 + h) * 2048) + s) * 256 + d] = val;
          } else if (n0 < 3072) {    // K region
            int kv = (n - 2048) >> 8, d = n & 255;
            k_out[(((size_t)(b * 4 + kv) * 2048) + s) * 256 + d] = val;
          } else {                   // V region, transposed store [b][kv][d][s]
            int kv = (n - 3072) >> 8, d = n & 255;
            vT_out[(((size_t)(b * 4 + kv) * 256) + d) * 2048 + s] = val;
          }
        }
  }
}

// ------------------------------------------------------- RMSNorm + RoPE (in place)
// rows 0..32767: Q rows [b*8+h][s]; rows 32768..49151: K rows [b*4+kv][s]
__global__ __launch_bounds__(256) void norm_rope(
    unsigned short* __restrict__ Qb, unsigned short* __restrict__ Kb,
    const float* __restrict__ cosb, const float* __restrict__ sinb,
    const float* __restrict__ qw, const float* __restrict__ kw) {
  const int row = blockIdx.x * 4 + (threadIdx.x >> 6);
  const int l = threadIdx.x & 63;
  unsigned short* base;
  int b, s;
  const float* wp;
  if (row < 32768) {
    base = Qb + (size_t)row * 256;
    b = row >> 14; s = row & 2047; wp = qw;
  } else {
    int r = row - 32768;
    base = Kb + (size_t)r * 256;
    b = r >> 13; s = r & 2047; wp = kw;
  }
  const int d = l * 4;
  ushort4 xu = *(const ushort4*)(base + d);
  float x0 = b2f(xu.x), x1 = b2f(xu.y), x2 = b2f(xu.z), x3 = b2f(xu.w);
  float ss = x0 * x0 + x1 * x1 + x2 * x2 + x3 * x3;
#pragma unroll
  for (int mk = 1; mk < 64; mk <<= 1) ss += __shfl_xor(ss, mk, 64);
  const float rinv = rsqrtf(ss * (1.0f / 256.0f) + 1e-6f);
  const float4 wv = *(const float4*)(wp + d);
  float n0 = x0 * rinv * (1.f + wv.x);
  float n1 = x1 * rinv * (1.f + wv.y);
  float n2 = x2 * rinv * (1.f + wv.z);
  float n3 = x3 * rinv * (1.f + wv.w);
  // rotate_half partner lives in lane ^ 32 (d ^ 128), same sub-index
  float p0 = __shfl_xor(n0, 32, 64);
  float p1 = __shfl_xor(n1, 32, 64);
  float p2 = __shfl_xor(n2, 32, 64);
  float p3 = __shfl_xor(n3, 32, 64);
  const float sgn = (l < 32) ? -1.f : 1.f;
  const size_t cofs = ((size_t)(b * 2048 + s)) * 256 + d;
  const float4 cv = *(const float4*)(cosb + cofs);
  const float4 sv = *(const float4*)(sinb + cofs);
  xu.x = f2b(n0 * cv.x + sgn * p0 * sv.x);
  xu.y = f2b(n1 * cv.y + sgn * p1 * sv.y);
  xu.z = f2b(n2 * cv.z + sgn * p2 * sv.z);
  xu.w = f2b(n3 * cv.w + sgn * p3 * sv.w);
  *(ushort4*)(base + d) = xu;
}

// ---------------------------------------------------------------- flash attention
// grid (qt=32, h=8, b=2), 256 thr = 4 waves, each wave 16 q-rows; KVBLK=64.
// LDS 64KB: Ks[64][256] (swz bit9-11->4-6) | Vs=VT[256][64] (swz bit7-9->4-6);
// P (per-wave 16x64) aliases the dead Ks region after QK^T.
__global__ __launch_bounds__(256) void attn_fwd(
    const unsigned short* __restrict__ Qb,
    const unsigned short* __restrict__ Kb,
    const unsigned short* __restrict__ VTb,
    unsigned short* __restrict__ Ob) {
  __shared__ __align__(16) unsigned char smem[65536];
  unsigned short* Ks = (unsigned short*)smem;            // 32KB
  const char* Vsc = (const char*)(smem + 32768);         // 32KB
  const int t = threadIdx.x, w = t >> 6, l = t & 63;
  const int qt = blockIdx.x, h = blockIdx.y, b = blockIdx.z;
  const int kvh = h >> 1;
  const int i0 = qt * 64, iw = i0 + w * 16;
  const int lr = l & 15, g = l >> 4, g4 = g * 4;
  char* PsB = (char*)(smem + w * 2048);                  // aliases Ks region

  bf16x8 qf[8];
  {
    const unsigned short* qrow = Qb + (((size_t)(b * 8 + h) * 2048) + iw + lr) * 256;
#pragma unroll
    for (int ks = 0; ks < 8; ks++) qf[ks] = *(const bf16x8*)(qrow + ks * 32 + g * 8);
  }
  f32x4 accO[16] = {};
  float mrow[4] = {-3e38f, -3e38f, -3e38f, -3e38f};
  float lrow[4] = {0.f, 0.f, 0.f, 0.f};

  const int jt0 = (qt >= 16) ? (qt - 16) : 0;
  const unsigned short* Kt  = Kb  + ((size_t)(b * 4 + kvh) * 2048) * 256;
  const unsigned short* VTt = VTb + ((size_t)(b * 4 + kvh) * 256) * 2048;

  for (int jt = jt0; jt <= qt; jt++) {
    // ---- stage K (contiguous 32KB) and V^T (256 rows x 128B) with swizzled sources
    const char* Kg = (const char*)(Kt + (size_t)jt * 64 * 256);
#pragma unroll
    for (int qq = 0; qq < 8; qq++) {
      int L = t * 16 + qq * 4096;
      int Lsw = L ^ (((L >> 9) & 7) << 4);
      gl_lds16(Kg + Lsw, (char*)Ks + L);
    }
#pragma unroll
    for (int qq = 0; qq < 8; qq++) {
      int L = t * 16 + qq * 4096;
      int Ls = L ^ (((L >> 7) & 7) << 4);
      int dd = Ls >> 7, kb = Ls & 127;
      const char* src = (const char*)(VTt + (size_t)dd * 2048 + (size_t)jt * 64) + kb;
      gl_lds16(src, (char*)smem + 32768 + L);
    }
    __syncthreads();

    // ---- QK^T : A=Q rows, B=K rows(as cols)
    f32x4 sc[4];
#pragma unroll
    for (int fn = 0; fn < 4; fn++) {
      f32x4 a = {0.f, 0.f, 0.f, 0.f};
      int j = fn * 16 + lr;
#pragma unroll
      for (int ks = 0; ks < 8; ks++) {
        int byteo = j * 512 + ks * 64 + g * 16;
        int sb = byteo ^ (((byteo >> 9) & 7) << 4);
        bf16x8 kf = *(const bf16x8*)((const char*)Ks + sb);
        a = MFMA16x16(qf[ks], kf, a);
      }
      sc[fn] = a;
    }

    // ---- softcap + mask + online softmax
    const int jbase = jt * 64;
    float sv4[4][4];
#pragma unroll
    for (int fn = 0; fn < 4; fn++) {
      int j = jbase + fn * 16 + lr;
#pragma unroll
      for (int r = 0; r < 4; r++) {
        float s = sc[fn][r];
        float xx = s * 0.00125f;               // s * (1/16) / 50
        float e2 = __expf(xx + xx);
        s = 50.f * (e2 - 1.f) / (e2 + 1.f);    // 50*tanh
        int i = iw + g4 + r;
        bool ok = (j <= i) && (j > i - 1024);
        sv4[r][fn] = ok ? s : -1e9f;
      }
    }
    float pw[4][4];
#pragma unroll
    for (int r = 0; r < 4; r++) {
      float pm = fmaxf(fmaxf(sv4[r][0], sv4[r][1]), fmaxf(sv4[r][2], sv4[r][3]));
      pm = fmaxf(pm, __shfl_xor(pm, 1, 64));
      pm = fmaxf(pm, __shfl_xor(pm, 2, 64));
      pm = fmaxf(pm, __shfl_xor(pm, 4, 64));
      pm = fmaxf(pm, __shfl_xor(pm, 8, 64));
      float mnew = fmaxf(mrow[r], pm);
      float alpha = __expf(mrow[r] - mnew);
      mrow[r] = mnew;
      float ps = 0.f;
#pragma unroll
      for (int fn = 0; fn < 4; fn++) {
        float p = __expf(sv4[r][fn] - mnew);
        pw[r][fn] = p; ps += p;
      }
      ps += __shfl_xor(ps, 1, 64);
      ps += __shfl_xor(ps, 2, 64);
      ps += __shfl_xor(ps, 4, 64);
      ps += __shfl_xor(ps, 8, 64);
      lrow[r] = lrow[r] * alpha + ps;
#pragma unroll
      for (int fd = 0; fd < 16; fd++) accO[fd][r] *= alpha;
    }

    __syncthreads();   // all waves done reading Ks -> safe to overwrite with P
#pragma unroll
    for (int r = 0; r < 4; r++)
#pragma unroll
      for (int fn = 0; fn < 4; fn++) {
        int byteo = (g4 + r) * 128 + (fn * 16 + lr) * 2;
        int sb = byteo ^ (((byteo >> 7) & 7) << 4);
        *(unsigned short*)(PsB + sb) = f2b(pw[r][fn]);
      }
    __syncthreads();   // P visible

    // ---- PV : A=P rows, B=V^T rows(as cols)
    bf16x8 pf[2];
#pragma unroll
    for (int k2 = 0; k2 < 2; k2++) {
      int byteo = lr * 128 + k2 * 64 + g * 16;
      int sb = byteo ^ (((byteo >> 7) & 7) << 4);
      pf[k2] = *(const bf16x8*)(PsB + sb);
    }
#pragma unroll
    for (int fd = 0; fd < 16; fd++) {
#pragma unroll
      for (int k2 = 0; k2 < 2; k2++) {
        int vb = (fd * 16 + lr) * 128 + k2 * 64 + g * 16;
        int sb = vb ^ (((vb >> 7) & 7) << 4);
        bf16x8 vf = *(const bf16x8*)(Vsc + sb);
        accO[fd] = MFMA16x16(pf[k2], vf, accO[fd]);
      }
    }
    __syncthreads();   // done with Vs & P before next stage
  }

  float inv[4];
#pragma unroll
  for (int r = 0; r < 4; r++) inv[r] = 1.f / lrow[r];
#pragma unroll
  for (int fd = 0; fd < 16; fd++)
#pragma unroll
    for (int r = 0; r < 4; r++) {
      int i = iw + g4 + r;
      int dd = fd * 16 + lr;
      Ob[((size_t)(b * 2048 + i)) * 2048 + h * 256 + dd] = f2b(accO[fd][r] * inv[r]);
    }
}

// ---------------------------------------------------------------- launcher
extern "C" void kernel_launch(void* const* d_in, const int* in_sizes, int n_in,
                              void* d_out, int out_size, void* d_ws, size_t ws_size,
                              hipStream_t stream) {
  (void)in_sizes; (void)n_in; (void)out_size; (void)ws_size;
  const float* hs   = (const float*)d_in[0];
  const float* cosb = (const float*)d_in[1];
  const float* sinb = (const float*)d_in[2];
  // d_in[3] = attention_mask (computed analytically)
  const float* wq   = (const float*)d_in[4];
  const float* wk   = (const float*)d_in[5];
  const float* wv   = (const float*)d_in[6];
  const float* wo   = (const float*)d_in[7];
  const float* qnw  = (const float*)d_in[8];
  const float* knw  = (const float*)d_in[9];

  char* ws = (char*)d_ws;
  unsigned short* Xbf  = (unsigned short*)(ws);              // 4096x2560   (21.0MB)
  unsigned short* Wqkv = (unsigned short*)(ws + 20971520);   // 4096x2560   (21.0MB)
  unsigned short* Wob  = (unsigned short*)(ws + 41943040);   // 2560x2048   (10.5MB)
  unsigned short* Qb   = (unsigned short*)(ws + 52428800);   // [2][8][2048][256]
  unsigned short* Kb   = (unsigned short*)(ws + 69206016);   // [2][4][2048][256]
  unsigned short* VT   = (unsigned short*)(ws + 77594624);   // [2][4][256][2048]
  unsigned short* AO   = (unsigned short*)(ws + 85983232);   // 4096x2048   (16.8MB)

  cast_f32_bf16<<<2048, 256, 0, stream>>>(hs, Xbf, 10485760 / 4);
  cast_f32_bf16<<<1024, 256, 0, stream>>>(wq, Wqkv, 5242880 / 4);
  cast_f32_bf16<<<512,  256, 0, stream>>>(wk, Wqkv + 5242880, 2621440 / 4);
  cast_f32_bf16<<<512,  256, 0, stream>>>(wv, Wqkv + 7864320, 2621440 / 4);
  cast_f32_bf16<<<1024, 256, 0, stream>>>(wo, Wob, 5242880 / 4);

  dim3 g0(32, 32);
  gemm_bt<0><<<g0, 256, 0, stream>>>(Xbf, Wqkv, 2560, Qb, Kb, VT, nullptr, 0);

  norm_rope<<<12288, 256, 0, stream>>>(Qb, Kb, cosb, sinb, qnw, knw);

  dim3 ga(32, 8, 2);
  attn_fwd<<<ga, 256, 0, stream>>>(Qb, Kb, VT, AO);

  dim3 g1(32, 20);
  gemm_bt<1><<<g1, 256, 0, stream>>>(AO, Wob, 2048, nullptr, nullptr, nullptr,
                                     (float*)d_out, 2560);
}